// Round 18
// baseline (448.258 us; speedup 1.0000x reference)
//
#include <hip/hip_runtime.h>
#include <hip/hip_bf16.h>
#include <math.h>

#define NN 50000
#define NE 400000
#define DIM 64
#define HEADS 4
#define SIC 0.5f
#define NBLK ((NN + 255) / 256)   // 196

typedef _Float16 f16x8 __attribute__((ext_vector_type(8)));
typedef _Float16 f16x2 __attribute__((ext_vector_type(2)));
typedef float f32x4 __attribute__((ext_vector_type(4)));

__device__ __forceinline__ unsigned pack_f16c(float re, float im) {
    f16x2 p; p[0] = (_Float16)re; p[1] = (_Float16)im;
    return __builtin_bit_cast(unsigned, p);
}

// (-b, a) from (a, b)
__device__ __forceinline__ f16x2 swapneg(f16x2 v) {
    unsigned u = __builtin_bit_cast(unsigned, v);
    u = ((u >> 16) | (u << 16)) ^ 0x8000u;
    return __builtin_bit_cast(f16x2, u);
}

// sum over 8-lane group via DPP: quad_perm xor1, quad_perm xor2, row_half_mirror
__device__ __forceinline__ float dpp_red8(float x) {
    int xi = __builtin_bit_cast(int, x);
    x += __builtin_bit_cast(float, __builtin_amdgcn_update_dpp(0, xi, 0xB1, 0xF, 0xF, true));
    xi = __builtin_bit_cast(int, x);
    x += __builtin_bit_cast(float, __builtin_amdgcn_update_dpp(0, xi, 0x4E, 0xF, 0xF, true));
    xi = __builtin_bit_cast(int, x);
    x += __builtin_bit_cast(float, __builtin_amdgcn_update_dpp(0, xi, 0x141, 0xF, 0xF, true));
    return x;
}
// sum over 16-lane group: + ROW_MIRROR (0x140)
__device__ __forceinline__ float dpp_red16(float x) {
    x = dpp_red8(x);
    int xi = __builtin_bit_cast(int, x);
    x += __builtin_bit_cast(float, __builtin_amdgcn_update_dpp(0, xi, 0x140, 0xF, 0xF, true));
    return x;
}

// ---------------- k_pre: weight tables (interleaved-k) + P16 + degree count -----------
// B2c: fragment-contiguous k5 table: element (ch,nt,slot,j) at ch*4096+nt*512+slot*8+j
//   maps to logical B2[c_out=nt*16+(slot>>2)][k=ch*32+(slot&3)*8+j]
#define SA (512 * 128)
#define SB (SA + 512 * 128)
#define SC (SB + 128 * 512)
#define SD (SC + NN * 64)
#define SE (SD + NE)
__global__ void k_pre(const float* __restrict__ h_re, const float* __restrict__ h_im,
                      const float* __restrict__ Wre, const float* __restrict__ Wim,
                      const float* __restrict__ Qre, const float* __restrict__ Qim,
                      const int* __restrict__ dst,
                      _Float16* __restrict__ BtQ, _Float16* __restrict__ BtWH,
                      _Float16* __restrict__ B2c, unsigned* __restrict__ P16,
                      int* __restrict__ counts, int* __restrict__ bsum) {
    int tid = blockIdx.x * blockDim.x + threadIdx.x;
    if (tid < SA) {
        int c = tid >> 7, k = tid & 127;
        int mh = c >> 7, cm = c & 127;
        int comp = cm >> 6, o = cm & 63;
        int i = k >> 1, cin = k & 1;
        int widx = (mh * DIM + o) * DIM + i;     // Q[o][i]
        float v;
        if (cin == 0) v = comp ? Qim[widx] : Qre[widx];
        else          v = comp ? Qre[widx] : -Qim[widx];
        BtQ[tid] = (_Float16)v;
    } else if (tid < SB) {
        int t2 = tid - SA;
        int c = t2 >> 7, k = t2 & 127;
        int mh = c >> 7, cm = c & 127;
        int comp = cm >> 6, o = cm & 63;
        int i = k >> 1, cin = k & 1;
        int widx = (mh * DIM + i) * DIM + o;     // W[i][o] (conj-transpose)
        float v;
        if (cin == 0) v = comp ? -Wim[widx] : Wre[widx];
        else          v = comp ?  Wre[widx] : Wim[widx];
        BtWH[t2] = (_Float16)v;
    } else if (tid < SC) {
        int t2 = tid - SB;
        int ch = t2 >> 12;
        int rem = t2 & 4095;
        int nt = rem >> 9;
        int rem2 = rem & 511;
        int slot = rem2 >> 3, j = rem2 & 7;
        int c_out = nt * 16 + (slot >> 2);
        int k = ch * 32 + (slot & 3) * 8 + j;
        int comp_out = c_out >> 6, o = c_out & 63;
        int m = k >> 7, cin = k & 1, i = (k >> 1) & 63;
        int widx = (m * DIM + o) * DIM + i;
        float v;
        if (cin == 0) v = comp_out ? Wim[widx] : Wre[widx];
        else          v = comp_out ? Wre[widx] : -Wim[widx];
        B2c[t2] = (_Float16)v;
    } else if (tid < SD) {
        int t2 = tid - SC;
        int n = t2 >> 6, d = t2 & 63;
        P16[t2] = pack_f16c(h_re[n * 64 + d], h_im[n * 64 + d]);
    } else if (tid < SE) {
        int e = tid - SD;
        int dn = dst[e];
        atomicAdd(&counts[dn], 1);
        atomicAdd(&bsum[dn >> 8], 1);    // per-scan-block sums (replaces k2b1)
    }
}

// ---------------- k1f: fused Qh GEMM -> kappa/y -> w = W^H y GEMM (LDS-resident) ------
// 128-node chunks: LDS 34816 B -> 4 blocks/CU (2x occupancy of the 256-node version)
__global__ __launch_bounds__(256) void k1f(
    const unsigned* __restrict__ P16, const _Float16* __restrict__ BtQ,
    const _Float16* __restrict__ BtWH, unsigned* __restrict__ W16) {
    __shared__ unsigned Qy[128 * 68];   // 34816 B
    int b = blockIdx.x;
    int mh = b & 3, chunk = b >> 2;
    int w = threadIdx.x >> 6, l = threadIdx.x & 63;
    int r = l & 15, g = l >> 4;
    int nbase = chunk * 128;
    const _Float16* A = (const _Float16*)P16;

    // ---- phase 1: Qh = Q h (MFMA), output to LDS ----
    {
        f16x8 Wf[2][4];
#pragma unroll
        for (int t = 0; t < 2; ++t)
#pragma unroll
            for (int ch = 0; ch < 4; ++ch)
                Wf[t][ch] = *(const f16x8*)(BtQ + (mh * 128 + t * 64 + w * 16 + r) * 128 + ch * 32 + g * 8);

        f16x8 N[3][4];
#pragma unroll
        for (int p = 0; p < 2; ++p) {
            int nc = min(nbase + p * 16 + r, NN - 1);
#pragma unroll
            for (int ch = 0; ch < 4; ++ch)
                N[p][ch] = *(const f16x8*)(A + (size_t)nc * 128 + ch * 32 + g * 8);
        }

#pragma unroll
        for (int nt = 0; nt < 8; ++nt) {
            const int cur = nt % 3;
            if (nt + 2 < 8) {
                const int nxt = (nt + 2) % 3;
                int nc = min(nbase + (nt + 2) * 16 + r, NN - 1);
#pragma unroll
                for (int ch = 0; ch < 4; ++ch)
                    N[nxt][ch] = *(const f16x8*)(A + (size_t)nc * 128 + ch * 32 + g * 8);
            }
            f32x4 a0 = {0.f, 0.f, 0.f, 0.f}, a1 = {0.f, 0.f, 0.f, 0.f};
#pragma unroll
            for (int ch = 0; ch < 4; ++ch) {
                a0 = __builtin_amdgcn_mfma_f32_16x16x32_f16(Wf[0][ch], N[cur][ch], a0, 0, 0, 0);
                a1 = __builtin_amdgcn_mfma_f32_16x16x32_f16(Wf[1][ch], N[cur][ch], a1, 0, 0, 0);
            }
            uint4 u;
            u.x = pack_f16c(a0[0], a1[0]);
            u.y = pack_f16c(a0[1], a1[1]);
            u.z = pack_f16c(a0[2], a1[2]);
            u.w = pack_f16c(a0[3], a1[3]);
            int node = nt * 16 + r;
            *(uint4*)&Qy[node * 68 + w * 16 + g * 4] = u;
        }
    }
    __syncthreads();

    // ---- phase 2: per node (16-lane group): tnm, n2, kappa; y = Qh - conj(kappa) h ----
#pragma unroll 4
    for (int it = 0; it < 8; ++it) {
        int node = it * 16 + w * 4 + (l >> 4);
        int ll = l & 15, d0 = ll * 4;
        int n_glob = nbase + node;
        uint4 q = *(const uint4*)&Qy[node * 68 + d0];
        uint4 hp = make_uint4(0, 0, 0, 0);
        if (n_glob < NN) hp = *(const uint4*)&P16[(size_t)n_glob * 64 + d0];
        unsigned qw[4] = {q.x, q.y, q.z, q.w};
        unsigned hw[4] = {hp.x, hp.y, hp.z, hp.w};
        float qre[4], qim[4], hre[4], him[4];
        float tr = 0.f, ti = 0.f, n2 = 0.f;
#pragma unroll
        for (int j = 0; j < 4; ++j) {
            f16x2 pq = __builtin_bit_cast(f16x2, qw[j]);
            f16x2 ph = __builtin_bit_cast(f16x2, hw[j]);
            qre[j] = (float)pq[0]; qim[j] = (float)pq[1];
            hre[j] = (float)ph[0]; him[j] = (float)ph[1];
            tr += qre[j] * hre[j] + qim[j] * him[j];
            ti += qre[j] * him[j] - qim[j] * hre[j];
            n2 += hre[j] * hre[j] + him[j] * him[j];
        }
        tr = dpp_red16(tr); ti = dpp_red16(ti); n2 = dpp_red16(n2);
        float cfac = SIC / fmaxf(n2, 1e-6f);
        float kre = cfac * tr, kim = cfac * ti;
        uint4 y;
        unsigned* yp = &y.x;
#pragma unroll
        for (int j = 0; j < 4; ++j) {
            float yre = qre[j] - (kre * hre[j] + kim * him[j]);
            float yim = qim[j] - (kre * him[j] - kim * hre[j]);
            yp[j] = pack_f16c(yre, yim);
        }
        *(uint4*)&Qy[node * 68 + d0] = y;
    }
    __syncthreads();

    // ---- phase 3: w = W^H y (MFMA, A from LDS), write W16 ----
    {
        f16x8 Wf[2][4];
#pragma unroll
        for (int t = 0; t < 2; ++t)
#pragma unroll
            for (int ch = 0; ch < 4; ++ch)
                Wf[t][ch] = *(const f16x8*)(BtWH + (mh * 128 + t * 64 + w * 16 + r) * 128 + ch * 32 + g * 8);

#pragma unroll
        for (int nt = 0; nt < 8; ++nt) {
            f32x4 a0 = {0.f, 0.f, 0.f, 0.f}, a1 = {0.f, 0.f, 0.f, 0.f};
#pragma unroll
            for (int ch = 0; ch < 4; ++ch) {
                f16x8 nf = *(const f16x8*)&Qy[(nt * 16 + r) * 68 + ch * 16 + g * 4];
                a0 = __builtin_amdgcn_mfma_f32_16x16x32_f16(Wf[0][ch], nf, a0, 0, 0, 0);
                a1 = __builtin_amdgcn_mfma_f32_16x16x32_f16(Wf[1][ch], nf, a1, 0, 0, 0);
            }
            int n = nbase + nt * 16 + r;
            if (n < NN) {
                uint4 u;
                u.x = pack_f16c(a0[0], a1[0]);
                u.y = pack_f16c(a0[1], a1[1]);
                u.z = pack_f16c(a0[2], a1[2]);
                u.w = pack_f16c(a0[3], a1[3]);
                *(uint4*)&W16[((size_t)n * 4 + mh) * 64 + w * 16 + g * 4] = u;
            }
        }
    }
}

// ---------------- CSR build: scan over precomputed block sums ----------------
__global__ __launch_bounds__(256) void k2b2(const int* __restrict__ bsum,
                                            int* __restrict__ bpre) {
    __shared__ int buf[256];
    int t = threadIdx.x;
    int v = (t < NBLK) ? bsum[t] : 0;
    buf[t] = v;
    __syncthreads();
    for (int off = 1; off < 256; off <<= 1) {
        int x = 0;
        if (t >= off) x = buf[t - off];
        __syncthreads();
        buf[t] += x;
        __syncthreads();
    }
    if (t < NBLK) bpre[t] = buf[t] - v;   // exclusive block prefix
}

__global__ __launch_bounds__(256) void k2b3(const int* __restrict__ counts,
                                            const int* __restrict__ bpre,
                                            int* __restrict__ row_ptr, int* __restrict__ cursor) {
    __shared__ int buf[256];
    int t = threadIdx.x;
    int i = blockIdx.x * 256 + t;
    int v = (i < NN) ? counts[i] : 0;
    buf[t] = v;
    __syncthreads();
    for (int off = 1; off < 256; off <<= 1) {
        int x = 0;
        if (t >= off) x = buf[t - off];
        __syncthreads();
        buf[t] += x;
        __syncthreads();
    }
    int excl = buf[t] - v + bpre[blockIdx.x];
    if (i < NN) { row_ptr[i] = excl; cursor[i] = excl; }
    if (i == NN - 1) row_ptr[NN] = excl + v;
}

// store src << 8 = byte offset (h_re and P16 are both 256 B per node)
__global__ void k2c_fill(const int* __restrict__ src, const int* __restrict__ dst,
                         int* __restrict__ cursor, int* __restrict__ sorted_src) {
    int e = blockIdx.x * blockDim.x + threadIdx.x;
    if (e < NE) {
        int pos = atomicAdd(&cursor[dst[e]], 1);
        sorted_src[pos] = src[e] << 8;
    }
}

// ---------------- K_main: single w-dot per edge/head; packed-f16 S accumulation. ------
__global__ __launch_bounds__(128) void k_main(
    const float* __restrict__ h_re,
    const unsigned* __restrict__ P16,        // [NN][64] packed (re,im) f16
    const unsigned* __restrict__ W16,        // [NN][4][64] packed w
    const int* __restrict__ row_ptr, const int* __restrict__ sorted_src,
    _Float16* __restrict__ Sb) {
    int wave = threadIdx.x >> 6;
    int lane = threadIdx.x & 63;
    int n = blockIdx.x * 2 + wave;
    int e = lane >> 5;
    int g = (lane >> 3) & 3;
    int l = lane & 7;
    int d0 = l * 8;

    const char* hb = (const char*)h_re + d0 * 4;          // + s*256
    const char* pb = (const char*)P16 + d0 * 4;           // + s*256

    float hre[8];
    f16x2 w2[8], wn2[8];
    {
        float4 a0 = *(const float4*)(h_re + n * DIM + d0);
        float4 a1 = *(const float4*)(h_re + n * DIM + d0 + 4);
        hre[0] = a0.x; hre[1] = a0.y; hre[2] = a0.z; hre[3] = a0.w;
        hre[4] = a1.x; hre[5] = a1.y; hre[6] = a1.z; hre[7] = a1.w;
        const unsigned* wp = W16 + ((size_t)n * 4 + g) * 64 + d0;
        uint4 wa = *(const uint4*)wp, wb = *(const uint4*)(wp + 4);
        unsigned ww[8] = {wa.x, wa.y, wa.z, wa.w, wb.x, wb.y, wb.z, wb.w};
#pragma unroll
        for (int j = 0; j < 8; ++j) {
            w2[j] = __builtin_bit_cast(f16x2, ww[j]);
            wn2[j] = swapneg(w2[j]);
        }
    }

    int beg = row_ptr[n], end = row_ptr[n + 1];
    float l_run = 0.f;
    f16x2 ps[8];
#pragma unroll
    for (int j = 0; j < 8; ++j) ps[j] = f16x2{(_Float16)0.f, (_Float16)0.f};

    float4 aR0 = make_float4(0, 0, 0, 0), aR1 = aR0, bR0 = aR0, bR1 = aR0;
    uint4 aP0 = make_uint4(0, 0, 0, 0), aP1 = aP0, bP0 = aP0, bP1 = aP0;
    auto ldE = [&](int idx, float4& r0_, float4& r1_, uint4& p0_, uint4& p1_) {
        int soff = sorted_src[idx];
        r0_ = *(const float4*)(hb + soff);
        r1_ = *(const float4*)(hb + soff + 16);
        p0_ = *(const uint4*)(pb + soff);
        p1_ = *(const uint4*)(pb + soff + 16);
    };
    auto process = [&](const float4& R0, const float4& R1, const uint4& P0, const uint4& P1,
                       bool valid) {
        float csr[8] = {R0.x, R0.y, R0.z, R0.w, R1.x, R1.y, R1.z, R1.w};
        unsigned pw[8] = {P0.x, P0.y, P0.z, P0.w, P1.x, P1.y, P1.z, P1.w};
        float r2 = 0, r3 = 0, r4 = 0;
#pragma unroll
        for (int j = 0; j < 8; ++j) {
            f16x2 hs2 = __builtin_bit_cast(f16x2, pw[j]);
            r2 = __builtin_amdgcn_fdot2(w2[j], hs2, r2, false);
            r3 = __builtin_amdgcn_fdot2(wn2[j], hs2, r3, false);
            r4 = fmaf(hre[j], csr[j], r4);
        }
        r2 = dpp_red8(r2); r3 = dpp_red8(r3); r4 = dpp_red8(r4);

        float sg = (r4 > 0.f) ? 1.f : ((r4 < 0.f) ? 0.f : 0.5f);
        // exp(|s|/8) = exp2(|s| * 0.125*log2(e))
        float mag2 = sqrtf(r2 * r2 + r3 * r3) * 0.180336880f;
        float ex = valid ? __builtin_exp2f(mag2) : 0.f;
        float wgt = fminf(ex * sg, 30000.f);   // f16-overflow guard
        l_run += ex;
        _Float16 wh = (_Float16)wgt;
        f16x2 wv = {wh, wh};
#pragma unroll
        for (int j = 0; j < 8; ++j) {
            f16x2 hs2 = __builtin_bit_cast(f16x2, pw[j]);
            ps[j] = ps[j] + wv * hs2;      // v_pk_fma_f16
        }
    };

    if (beg + e < end) ldE(beg + e, aR0, aR1, aP0, aP1);
    if (beg + 2 + e < end) ldE(beg + 2 + e, bR0, bR1, bP0, bP1);

    for (int pos = beg; pos < end; pos += 4) {
        process(aR0, aR1, aP0, aP1, (pos + e) < end);
        if (pos + 4 + e < end) ldE(pos + 4 + e, aR0, aR1, aP0, aP1);
        else { aR0 = make_float4(0, 0, 0, 0); aR1 = aR0; aP0 = make_uint4(0, 0, 0, 0); aP1 = aP0; }
        if (pos + 2 >= end) break;
        process(bR0, bR1, bP0, bP1, (pos + 2 + e) < end);
        if (pos + 6 + e < end) ldE(pos + 6 + e, bR0, bR1, bP0, bP1);
        else { bR0 = make_float4(0, 0, 0, 0); bR1 = bR0; bP0 = make_uint4(0, 0, 0, 0); bP1 = bP0; }
    }

    // merge the two halves (packed adds)
#pragma unroll
    for (int j = 0; j < 8; ++j) {
        unsigned o = __shfl_xor(__builtin_bit_cast(unsigned, ps[j]), 32, 64);
        ps[j] = ps[j] + __builtin_bit_cast(f16x2, o);
    }
    l_run += __shfl_xor(l_run, 32, 64);

    // deg-0 nodes: l_run == 0 -> S must be 0 (NOT inf; (f16)1e16 = inf, 0*inf = NaN)
    float inv = (l_run > 0.f) ? (1.0f / l_run) : 0.f;
    if (e == 0) {
        _Float16 ih = (_Float16)inv;
        f16x2 iv = {ih, ih};
        uint4 o0, o1;
        unsigned* op0 = &o0.x;
        unsigned* op1 = &o1.x;
#pragma unroll
        for (int j = 0; j < 4; ++j) {
            op0[j] = __builtin_bit_cast(unsigned, (f16x2)(ps[j] * iv));
            op1[j] = __builtin_bit_cast(unsigned, (f16x2)(ps[j + 4] * iv));
        }
        _Float16* sp = Sb + (size_t)n * 512 + g * 128 + d0 * 2;
        *(uint4*)sp = o0;
        *(uint4*)(sp + 8) = o1;
    }
}

// ---------------- K5_ws v2: 32 nodes/block, column-split wave pairs -------------------
__global__ __launch_bounds__(256) void k5_ws(
    const float* __restrict__ h_re, const float* __restrict__ h_im,
    const _Float16* __restrict__ Sb,
    const _Float16* __restrict__ B2c,
    const float* __restrict__ gate_raw, const float* __restrict__ modrelu_b,
    float2* __restrict__ out) {
    __shared__ float xch[2][32][8];
    int w = threadIdx.x >> 6, l = threadIdx.x & 63;
    int r = l & 15, g = l >> 4;
    int nh = w >> 1, ct = w & 1;
    int nbase = blockIdx.x * 32;
    int n0 = nbase + nh * 16;
    int nodeA = min(n0 + r, NN - 1);
    int q0 = 2 * ct;
    const int nt_[4] = {q0, q0 + 1, 4 + q0, 5 + q0};
    int slot8 = ((r << 2) + g) << 3;

    const _Float16* abase = Sb + (size_t)nodeA * 512 + g * 8;
    const _Float16* bbase = B2c + slot8;

    f32x4 acc[4];
#pragma unroll
    for (int t = 0; t < 4; ++t) acc[t] = {0.f, 0.f, 0.f, 0.f};

    f16x8 Ac = *(const f16x8*)(abase);
    f16x8 Bc0 = *(const f16x8*)(bbase + nt_[0] * 512);
    f16x8 Bc1 = *(const f16x8*)(bbase + nt_[1] * 512);
    f16x8 Bc2 = *(const f16x8*)(bbase + nt_[2] * 512);
    f16x8 Bc3 = *(const f16x8*)(bbase + nt_[3] * 512);
#pragma unroll
    for (int ch = 0; ch < 16; ++ch) {
        f16x8 An = Ac, Bn0 = Bc0, Bn1 = Bc1, Bn2 = Bc2, Bn3 = Bc3;
        if (ch + 1 < 16) {
            An = *(const f16x8*)(abase + (ch + 1) * 32);
            const _Float16* bn = bbase + (ch + 1) * 4096;
            Bn0 = *(const f16x8*)(bn + nt_[0] * 512);
            Bn1 = *(const f16x8*)(bn + nt_[1] * 512);
            Bn2 = *(const f16x8*)(bn + nt_[2] * 512);
            Bn3 = *(const f16x8*)(bn + nt_[3] * 512);
        }
        acc[0] = __builtin_amdgcn_mfma_f32_16x16x32_f16(Ac, Bc0, acc[0], 0, 0, 0);
        acc[1] = __builtin_amdgcn_mfma_f32_16x16x32_f16(Ac, Bc1, acc[1], 0, 0, 0);
        acc[2] = __builtin_amdgcn_mfma_f32_16x16x32_f16(Ac, Bc2, acc[2], 0, 0, 0);
        acc[3] = __builtin_amdgcn_mfma_f32_16x16x32_f16(Ac, Bc3, acc[3], 0, 0, 0);
        Ac = An; Bc0 = Bn0; Bc1 = Bn1; Bc2 = Bn2; Bc3 = Bn3;
    }

    float gate = 1.0f / (1.0f + expf(-gate_raw[0]));
    float bo[2];
#pragma unroll
    for (int qq = 0; qq < 2; ++qq) bo[qq] = modrelu_b[(q0 + qq) * 16 + r];

    float hr[4][2], hi[4][2];
#pragma unroll
    for (int j = 0; j < 4; ++j) {
        int nc = min(n0 + g * 4 + j, NN - 1);
#pragma unroll
        for (int qq = 0; qq < 2; ++qq) {
            int o = (q0 + qq) * 16 + r;
            hr[j][qq] = h_re[nc * DIM + o];
            hi[j][qq] = h_im[nc * DIM + o];
        }
    }

    float tsr_p[4], tsi_p[4], hn2_p[4];
#pragma unroll
    for (int j = 0; j < 4; ++j) {
        float tsr = 0.f, tsi = 0.f, hn2 = 0.f;
#pragma unroll
        for (int qq = 0; qq < 2; ++qq) {
            float ur = acc[qq][j], ui = acc[2 + qq][j];
            tsr += hr[j][qq] * ur + hi[j][qq] * ui;
            tsi += hr[j][qq] * ui - hi[j][qq] * ur;
            hn2 += hr[j][qq] * hr[j][qq] + hi[j][qq] * hi[j][qq];
        }
#pragma unroll
        for (int off = 1; off < 16; off <<= 1) {
            tsr += __shfl_xor(tsr, off, 64);
            tsi += __shfl_xor(tsi, off, 64);
            hn2 += __shfl_xor(hn2, off, 64);
        }
        tsr_p[j] = tsr; tsi_p[j] = tsi; hn2_p[j] = hn2;
        if (r == 0) {
            int nloc = nh * 16 + g * 4 + j;
            xch[ct][nloc][0] = tsr;
            xch[ct][nloc][1] = tsi;
            xch[ct][nloc][2] = hn2;
        }
    }
    __syncthreads();

    float Tsr[4], Tsi[4];
#pragma unroll
    for (int j = 0; j < 4; ++j) {
        int nloc = nh * 16 + g * 4 + j;
        float tsr = tsr_p[j] + xch[1 - ct][nloc][0];
        float tsi = tsi_p[j] + xch[1 - ct][nloc][1];
        float hn2 = hn2_p[j] + xch[1 - ct][nloc][2];
        float cfac = gate * SIC / fmaxf(hn2, 1e-6f);
        Tsr[j] = cfac * tsr; Tsi[j] = cfac * tsi;
    }

    float xr_[4][2], xi_[4][2];
    float sr_p[4], si_p[4], qr_p[4], qi_p[4];
#pragma unroll
    for (int j = 0; j < 4; ++j) {
        float sr = 0.f, si = 0.f, qr = 0.f, qi = 0.f;
#pragma unroll
        for (int qq = 0; qq < 2; ++qq) {
            float hrv = hr[j][qq], hiv = hi[j][qq];
            float nre = hrv + acc[qq][j]     - (Tsr[j] * hrv - Tsi[j] * hiv);
            float nim = hiv + acc[2 + qq][j] - (Tsr[j] * hiv + Tsi[j] * hrv);
            xr_[j][qq] = nre; xi_[j][qq] = nim;
            sr += nre; si += nim; qr += nre * nre; qi += nim * nim;
        }
#pragma unroll
        for (int off = 1; off < 16; off <<= 1) {
            sr += __shfl_xor(sr, off, 64);
            si += __shfl_xor(si, off, 64);
            qr += __shfl_xor(qr, off, 64);
            qi += __shfl_xor(qi, off, 64);
        }
        sr_p[j] = sr; si_p[j] = si; qr_p[j] = qr; qi_p[j] = qi;
        if (r == 0) {
            int nloc = nh * 16 + g * 4 + j;
            xch[ct][nloc][4] = sr;
            xch[ct][nloc][5] = si;
            xch[ct][nloc][6] = qr;
            xch[ct][nloc][7] = qi;
        }
    }
    __syncthreads();

#pragma unroll
    for (int j = 0; j < 4; ++j) {
        int nloc = nh * 16 + g * 4 + j;
        int n = n0 + g * 4 + j;
        float sr = sr_p[j] + xch[1 - ct][nloc][4];
        float si = si_p[j] + xch[1 - ct][nloc][5];
        float qr = qr_p[j] + xch[1 - ct][nloc][6];
        float qi = qi_p[j] + xch[1 - ct][nloc][7];
        float mean_r = sr * (1.f / DIM), mean_i = si * (1.f / DIM);
        float var_r = (qr - DIM * mean_r * mean_r) * (1.f / (DIM - 1));
        float var_i = (qi - DIM * mean_i * mean_i) * (1.f / (DIM - 1));
        float std_r = fmaxf(sqrtf(fmaxf(var_r, 0.f)), 1e-5f);
        float std_i = fmaxf(sqrtf(fmaxf(var_i, 0.f)), 1e-5f);
        if (n < NN) {
#pragma unroll
            for (int qq = 0; qq < 2; ++qq) {
                float xr = (xr_[j][qq] - mean_r) / std_r;
                float xi = (xi_[j][qq] - mean_i) / std_i;
                float mag = fmaxf(sqrtf(xr * xr + xi * xi), 1e-6f);
                float gg = fmaxf(mag + bo[qq], 0.f);
                float sc = gg / mag;
                out[n * DIM + (q0 + qq) * 16 + r] = make_float2(xr * sc, xi * sc);
            }
        }
    }
}

extern "C" void kernel_launch(void* const* d_in, const int* in_sizes, int n_in,
                              void* d_out, int out_size, void* d_ws, size_t ws_size,
                              hipStream_t stream) {
    const float* h_re = (const float*)d_in[0];
    const float* h_im = (const float*)d_in[1];
    const float* W_re = (const float*)d_in[2];
    const float* W_im = (const float*)d_in[3];
    const float* Q_re = (const float*)d_in[4];
    const float* Q_im = (const float*)d_in[5];
    const float* gate_raw = (const float*)d_in[6];
    const float* b = (const float*)d_in[7];
    const int* src = (const int*)d_in[8];
    const int* dst = (const int*)d_in[9];

    char* ws = (char*)d_ws;
    size_t off = 0;
    auto alloc = [&](size_t bytes) {
        void* p = ws + off;
        off = (off + bytes + 255) & ~(size_t)255;
        return p;
    };
    _Float16* Sb = (_Float16*)alloc((size_t)NN * 512 * sizeof(_Float16));     // 51.2MB
    _Float16* BtQ = (_Float16*)alloc((size_t)512 * 128 * sizeof(_Float16));
    _Float16* BtWH = (_Float16*)alloc((size_t)512 * 128 * sizeof(_Float16));
    _Float16* B2c = (_Float16*)alloc((size_t)128 * 512 * sizeof(_Float16));
    unsigned* P16 = (unsigned*)alloc((size_t)NN * 64 * sizeof(unsigned));     // 12.8MB
    unsigned* W16 = (unsigned*)alloc((size_t)NN * 256 * sizeof(unsigned));    // 51.2MB
    int* counts = (int*)alloc((size_t)NN * sizeof(int));
    int* row_ptr = (int*)alloc((size_t)(NN + 1) * sizeof(int));
    int* cursor = (int*)alloc((size_t)NN * sizeof(int));
    int* sorted_src = (int*)alloc((size_t)NE * sizeof(int));
    int* bsum = (int*)alloc((size_t)NBLK * sizeof(int));
    int* bpre = (int*)alloc((size_t)(NBLK + 1) * sizeof(int));

    hipMemsetAsync(counts, 0, (size_t)NN * sizeof(int), stream);
    hipMemsetAsync(bsum, 0, (size_t)NBLK * sizeof(int), stream);
    k_pre<<<(SE + 255) / 256, 256, 0, stream>>>(h_re, h_im, W_re, W_im, Q_re, Q_im, dst,
                                                BtQ, BtWH, B2c, P16, counts, bsum);
    k1f<<<4 * ((NN + 127) / 128), 256, 0, stream>>>(P16, BtQ, BtWH, W16);
    k2b2<<<1, 256, 0, stream>>>(bsum, bpre);
    k2b3<<<NBLK, 256, 0, stream>>>(counts, bpre, row_ptr, cursor);
    k2c_fill<<<(NE + 255) / 256, 256, 0, stream>>>(src, dst, cursor, sorted_src);
    k_main<<<NN / 2, 128, 0, stream>>>(h_re, P16, W16, row_ptr, sorted_src, Sb);
    k5_ws<<<(NN + 31) / 32, 256, 0, stream>>>(h_re, h_im, Sb, B2c, gate_raw, b, (float2*)d_out);
}

// Round 19
// 227.669 us; speedup vs baseline: 1.9689x; 1.9689x over previous
//
#include <hip/hip_runtime.h>
#include <hip/hip_bf16.h>
#include <math.h>

#define NN 50000
#define NE 400000
#define DIM 64
#define HEADS 4
#define SIC 0.5f
#define NBLK ((NN + 255) / 256)   // 196

typedef _Float16 f16x8 __attribute__((ext_vector_type(8)));
typedef _Float16 f16x2 __attribute__((ext_vector_type(2)));
typedef float f32x4 __attribute__((ext_vector_type(4)));

__device__ __forceinline__ unsigned pack_f16c(float re, float im) {
    f16x2 p; p[0] = (_Float16)re; p[1] = (_Float16)im;
    return __builtin_bit_cast(unsigned, p);
}

// (-b, a) from (a, b)
__device__ __forceinline__ f16x2 swapneg(f16x2 v) {
    unsigned u = __builtin_bit_cast(unsigned, v);
    u = ((u >> 16) | (u << 16)) ^ 0x8000u;
    return __builtin_bit_cast(f16x2, u);
}

// sum over 8-lane group via DPP: quad_perm xor1, quad_perm xor2, row_half_mirror
__device__ __forceinline__ float dpp_red8(float x) {
    int xi = __builtin_bit_cast(int, x);
    x += __builtin_bit_cast(float, __builtin_amdgcn_update_dpp(0, xi, 0xB1, 0xF, 0xF, true));
    xi = __builtin_bit_cast(int, x);
    x += __builtin_bit_cast(float, __builtin_amdgcn_update_dpp(0, xi, 0x4E, 0xF, 0xF, true));
    xi = __builtin_bit_cast(int, x);
    x += __builtin_bit_cast(float, __builtin_amdgcn_update_dpp(0, xi, 0x141, 0xF, 0xF, true));
    return x;
}
// sum over 16-lane group: + ROW_MIRROR (0x140)
__device__ __forceinline__ float dpp_red16(float x) {
    x = dpp_red8(x);
    int xi = __builtin_bit_cast(int, x);
    x += __builtin_bit_cast(float, __builtin_amdgcn_update_dpp(0, xi, 0x140, 0xF, 0xF, true));
    return x;
}

// ---------------- k_pre: weight tables (interleaved-k) + P16 + degree count -----------
// B2c: fragment-contiguous k5 table: element (ch,nt,slot,j) at ch*4096+nt*512+slot*8+j
//   maps to logical B2[c_out=nt*16+(slot>>2)][k=ch*32+(slot&3)*8+j]
#define SA (512 * 128)
#define SB (SA + 512 * 128)
#define SC (SB + 128 * 512)
#define SD (SC + NN * 64)
#define SE (SD + NE)
__global__ void k_pre(const float* __restrict__ h_re, const float* __restrict__ h_im,
                      const float* __restrict__ Wre, const float* __restrict__ Wim,
                      const float* __restrict__ Qre, const float* __restrict__ Qim,
                      const int* __restrict__ dst,
                      _Float16* __restrict__ BtQ, _Float16* __restrict__ BtWH,
                      _Float16* __restrict__ B2c, unsigned* __restrict__ P16,
                      int* __restrict__ counts) {
    int tid = blockIdx.x * blockDim.x + threadIdx.x;
    if (tid < SA) {
        int c = tid >> 7, k = tid & 127;
        int mh = c >> 7, cm = c & 127;
        int comp = cm >> 6, o = cm & 63;
        int i = k >> 1, cin = k & 1;
        int widx = (mh * DIM + o) * DIM + i;     // Q[o][i]
        float v;
        if (cin == 0) v = comp ? Qim[widx] : Qre[widx];
        else          v = comp ? Qre[widx] : -Qim[widx];
        BtQ[tid] = (_Float16)v;
    } else if (tid < SB) {
        int t2 = tid - SA;
        int c = t2 >> 7, k = t2 & 127;
        int mh = c >> 7, cm = c & 127;
        int comp = cm >> 6, o = cm & 63;
        int i = k >> 1, cin = k & 1;
        int widx = (mh * DIM + i) * DIM + o;     // W[i][o] (conj-transpose)
        float v;
        if (cin == 0) v = comp ? -Wim[widx] : Wre[widx];
        else          v = comp ?  Wre[widx] : Wim[widx];
        BtWH[t2] = (_Float16)v;
    } else if (tid < SC) {
        int t2 = tid - SB;
        int ch = t2 >> 12;
        int rem = t2 & 4095;
        int nt = rem >> 9;
        int rem2 = rem & 511;
        int slot = rem2 >> 3, j = rem2 & 7;
        int c_out = nt * 16 + (slot >> 2);
        int k = ch * 32 + (slot & 3) * 8 + j;
        int comp_out = c_out >> 6, o = c_out & 63;
        int m = k >> 7, cin = k & 1, i = (k >> 1) & 63;
        int widx = (m * DIM + o) * DIM + i;
        float v;
        if (cin == 0) v = comp_out ? Wim[widx] : Wre[widx];
        else          v = comp_out ? Wre[widx] : -Wim[widx];
        B2c[t2] = (_Float16)v;
    } else if (tid < SD) {
        int t2 = tid - SC;
        int n = t2 >> 6, d = t2 & 63;
        P16[t2] = pack_f16c(h_re[n * 64 + d], h_im[n * 64 + d]);
    } else if (tid < SE) {
        int e = tid - SD;
        atomicAdd(&counts[dst[e]], 1);    // 50000 counters, ~8 hits each: no contention
    }
}

// ---------------- k1f: fused Qh GEMM -> kappa/y -> w = W^H y GEMM (LDS-resident) ------
// 128-node chunks: LDS 34816 B -> 4 blocks/CU (2x occupancy of the 256-node version)
__global__ __launch_bounds__(256) void k1f(
    const unsigned* __restrict__ P16, const _Float16* __restrict__ BtQ,
    const _Float16* __restrict__ BtWH, unsigned* __restrict__ W16) {
    __shared__ unsigned Qy[128 * 68];   // 34816 B
    int b = blockIdx.x;
    int mh = b & 3, chunk = b >> 2;
    int w = threadIdx.x >> 6, l = threadIdx.x & 63;
    int r = l & 15, g = l >> 4;
    int nbase = chunk * 128;
    const _Float16* A = (const _Float16*)P16;

    // ---- phase 1: Qh = Q h (MFMA), output to LDS ----
    {
        f16x8 Wf[2][4];
#pragma unroll
        for (int t = 0; t < 2; ++t)
#pragma unroll
            for (int ch = 0; ch < 4; ++ch)
                Wf[t][ch] = *(const f16x8*)(BtQ + (mh * 128 + t * 64 + w * 16 + r) * 128 + ch * 32 + g * 8);

        f16x8 N[3][4];
#pragma unroll
        for (int p = 0; p < 2; ++p) {
            int nc = min(nbase + p * 16 + r, NN - 1);
#pragma unroll
            for (int ch = 0; ch < 4; ++ch)
                N[p][ch] = *(const f16x8*)(A + (size_t)nc * 128 + ch * 32 + g * 8);
        }

#pragma unroll
        for (int nt = 0; nt < 8; ++nt) {
            const int cur = nt % 3;
            if (nt + 2 < 8) {
                const int nxt = (nt + 2) % 3;
                int nc = min(nbase + (nt + 2) * 16 + r, NN - 1);
#pragma unroll
                for (int ch = 0; ch < 4; ++ch)
                    N[nxt][ch] = *(const f16x8*)(A + (size_t)nc * 128 + ch * 32 + g * 8);
            }
            f32x4 a0 = {0.f, 0.f, 0.f, 0.f}, a1 = {0.f, 0.f, 0.f, 0.f};
#pragma unroll
            for (int ch = 0; ch < 4; ++ch) {
                a0 = __builtin_amdgcn_mfma_f32_16x16x32_f16(Wf[0][ch], N[cur][ch], a0, 0, 0, 0);
                a1 = __builtin_amdgcn_mfma_f32_16x16x32_f16(Wf[1][ch], N[cur][ch], a1, 0, 0, 0);
            }
            uint4 u;
            u.x = pack_f16c(a0[0], a1[0]);
            u.y = pack_f16c(a0[1], a1[1]);
            u.z = pack_f16c(a0[2], a1[2]);
            u.w = pack_f16c(a0[3], a1[3]);
            int node = nt * 16 + r;
            *(uint4*)&Qy[node * 68 + w * 16 + g * 4] = u;
        }
    }
    __syncthreads();

    // ---- phase 2: per node (16-lane group): tnm, n2, kappa; y = Qh - conj(kappa) h ----
#pragma unroll 4
    for (int it = 0; it < 8; ++it) {
        int node = it * 16 + w * 4 + (l >> 4);
        int ll = l & 15, d0 = ll * 4;
        int n_glob = nbase + node;
        uint4 q = *(const uint4*)&Qy[node * 68 + d0];
        uint4 hp = make_uint4(0, 0, 0, 0);
        if (n_glob < NN) hp = *(const uint4*)&P16[(size_t)n_glob * 64 + d0];
        unsigned qw[4] = {q.x, q.y, q.z, q.w};
        unsigned hw[4] = {hp.x, hp.y, hp.z, hp.w};
        float qre[4], qim[4], hre[4], him[4];
        float tr = 0.f, ti = 0.f, n2 = 0.f;
#pragma unroll
        for (int j = 0; j < 4; ++j) {
            f16x2 pq = __builtin_bit_cast(f16x2, qw[j]);
            f16x2 ph = __builtin_bit_cast(f16x2, hw[j]);
            qre[j] = (float)pq[0]; qim[j] = (float)pq[1];
            hre[j] = (float)ph[0]; him[j] = (float)ph[1];
            tr += qre[j] * hre[j] + qim[j] * him[j];
            ti += qre[j] * him[j] - qim[j] * hre[j];
            n2 += hre[j] * hre[j] + him[j] * him[j];
        }
        tr = dpp_red16(tr); ti = dpp_red16(ti); n2 = dpp_red16(n2);
        float cfac = SIC / fmaxf(n2, 1e-6f);
        float kre = cfac * tr, kim = cfac * ti;
        uint4 y;
        unsigned* yp = &y.x;
#pragma unroll
        for (int j = 0; j < 4; ++j) {
            float yre = qre[j] - (kre * hre[j] + kim * him[j]);
            float yim = qim[j] - (kre * him[j] - kim * hre[j]);
            yp[j] = pack_f16c(yre, yim);
        }
        *(uint4*)&Qy[node * 68 + d0] = y;
    }
    __syncthreads();

    // ---- phase 3: w = W^H y (MFMA, A from LDS), write W16 ----
    {
        f16x8 Wf[2][4];
#pragma unroll
        for (int t = 0; t < 2; ++t)
#pragma unroll
            for (int ch = 0; ch < 4; ++ch)
                Wf[t][ch] = *(const f16x8*)(BtWH + (mh * 128 + t * 64 + w * 16 + r) * 128 + ch * 32 + g * 8);

#pragma unroll
        for (int nt = 0; nt < 8; ++nt) {
            f32x4 a0 = {0.f, 0.f, 0.f, 0.f}, a1 = {0.f, 0.f, 0.f, 0.f};
#pragma unroll
            for (int ch = 0; ch < 4; ++ch) {
                f16x8 nf = *(const f16x8*)&Qy[(nt * 16 + r) * 68 + ch * 16 + g * 4];
                a0 = __builtin_amdgcn_mfma_f32_16x16x32_f16(Wf[0][ch], nf, a0, 0, 0, 0);
                a1 = __builtin_amdgcn_mfma_f32_16x16x32_f16(Wf[1][ch], nf, a1, 0, 0, 0);
            }
            int n = nbase + nt * 16 + r;
            if (n < NN) {
                uint4 u;
                u.x = pack_f16c(a0[0], a1[0]);
                u.y = pack_f16c(a0[1], a1[1]);
                u.z = pack_f16c(a0[2], a1[2]);
                u.w = pack_f16c(a0[3], a1[3]);
                *(uint4*)&W16[((size_t)n * 4 + mh) * 64 + w * 16 + g * 4] = u;
            }
        }
    }
}

// ---------------- CSR build: 3-phase parallel scan ----------------
__global__ __launch_bounds__(256) void k2b1(const int* __restrict__ counts,
                                            int* __restrict__ bsum) {
    __shared__ int red[256];
    int t = threadIdx.x;
    int i = blockIdx.x * 256 + t;
    red[t] = (i < NN) ? counts[i] : 0;
    __syncthreads();
    for (int off = 128; off; off >>= 1) {
        if (t < off) red[t] += red[t + off];
        __syncthreads();
    }
    if (t == 0) bsum[blockIdx.x] = red[0];
}

__global__ __launch_bounds__(256) void k2b2(const int* __restrict__ bsum,
                                            int* __restrict__ bpre) {
    __shared__ int buf[256];
    int t = threadIdx.x;
    int v = (t < NBLK) ? bsum[t] : 0;
    buf[t] = v;
    __syncthreads();
    for (int off = 1; off < 256; off <<= 1) {
        int x = 0;
        if (t >= off) x = buf[t - off];
        __syncthreads();
        buf[t] += x;
        __syncthreads();
    }
    if (t < NBLK) bpre[t] = buf[t] - v;   // exclusive block prefix
}

__global__ __launch_bounds__(256) void k2b3(const int* __restrict__ counts,
                                            const int* __restrict__ bpre,
                                            int* __restrict__ row_ptr, int* __restrict__ cursor) {
    __shared__ int buf[256];
    int t = threadIdx.x;
    int i = blockIdx.x * 256 + t;
    int v = (i < NN) ? counts[i] : 0;
    buf[t] = v;
    __syncthreads();
    for (int off = 1; off < 256; off <<= 1) {
        int x = 0;
        if (t >= off) x = buf[t - off];
        __syncthreads();
        buf[t] += x;
        __syncthreads();
    }
    int excl = buf[t] - v + bpre[blockIdx.x];
    if (i < NN) { row_ptr[i] = excl; cursor[i] = excl; }
    if (i == NN - 1) row_ptr[NN] = excl + v;
}

// store src << 8 = byte offset (h_re and P16 are both 256 B per node)
__global__ void k2c_fill(const int* __restrict__ src, const int* __restrict__ dst,
                         int* __restrict__ cursor, int* __restrict__ sorted_src) {
    int e = blockIdx.x * blockDim.x + threadIdx.x;
    if (e < NE) {
        int pos = atomicAdd(&cursor[dst[e]], 1);
        sorted_src[pos] = src[e] << 8;
    }
}

// ---------------- K_main: single w-dot per edge/head; packed-f16 S accumulation. ------
__global__ __launch_bounds__(128) void k_main(
    const float* __restrict__ h_re,
    const unsigned* __restrict__ P16,        // [NN][64] packed (re,im) f16
    const unsigned* __restrict__ W16,        // [NN][4][64] packed w
    const int* __restrict__ row_ptr, const int* __restrict__ sorted_src,
    _Float16* __restrict__ Sb) {
    int wave = threadIdx.x >> 6;
    int lane = threadIdx.x & 63;
    int n = blockIdx.x * 2 + wave;
    int e = lane >> 5;
    int g = (lane >> 3) & 3;
    int l = lane & 7;
    int d0 = l * 8;

    const char* hb = (const char*)h_re + d0 * 4;          // + s*256
    const char* pb = (const char*)P16 + d0 * 4;           // + s*256

    float hre[8];
    f16x2 w2[8], wn2[8];
    {
        float4 a0 = *(const float4*)(h_re + n * DIM + d0);
        float4 a1 = *(const float4*)(h_re + n * DIM + d0 + 4);
        hre[0] = a0.x; hre[1] = a0.y; hre[2] = a0.z; hre[3] = a0.w;
        hre[4] = a1.x; hre[5] = a1.y; hre[6] = a1.z; hre[7] = a1.w;
        const unsigned* wp = W16 + ((size_t)n * 4 + g) * 64 + d0;
        uint4 wa = *(const uint4*)wp, wb = *(const uint4*)(wp + 4);
        unsigned ww[8] = {wa.x, wa.y, wa.z, wa.w, wb.x, wb.y, wb.z, wb.w};
#pragma unroll
        for (int j = 0; j < 8; ++j) {
            w2[j] = __builtin_bit_cast(f16x2, ww[j]);
            wn2[j] = swapneg(w2[j]);
        }
    }

    int beg = row_ptr[n], end = row_ptr[n + 1];
    float l_run = 0.f;
    f16x2 ps[8];
#pragma unroll
    for (int j = 0; j < 8; ++j) ps[j] = f16x2{(_Float16)0.f, (_Float16)0.f};

    float4 aR0 = make_float4(0, 0, 0, 0), aR1 = aR0, bR0 = aR0, bR1 = aR0;
    uint4 aP0 = make_uint4(0, 0, 0, 0), aP1 = aP0, bP0 = aP0, bP1 = aP0;
    auto ldE = [&](int idx, float4& r0_, float4& r1_, uint4& p0_, uint4& p1_) {
        int soff = sorted_src[idx];
        r0_ = *(const float4*)(hb + soff);
        r1_ = *(const float4*)(hb + soff + 16);
        p0_ = *(const uint4*)(pb + soff);
        p1_ = *(const uint4*)(pb + soff + 16);
    };
    auto process = [&](const float4& R0, const float4& R1, const uint4& P0, const uint4& P1,
                       bool valid) {
        float csr[8] = {R0.x, R0.y, R0.z, R0.w, R1.x, R1.y, R1.z, R1.w};
        unsigned pw[8] = {P0.x, P0.y, P0.z, P0.w, P1.x, P1.y, P1.z, P1.w};
        float r2 = 0, r3 = 0, r4 = 0;
#pragma unroll
        for (int j = 0; j < 8; ++j) {
            f16x2 hs2 = __builtin_bit_cast(f16x2, pw[j]);
            r2 = __builtin_amdgcn_fdot2(w2[j], hs2, r2, false);
            r3 = __builtin_amdgcn_fdot2(wn2[j], hs2, r3, false);
            r4 = fmaf(hre[j], csr[j], r4);
        }
        r2 = dpp_red8(r2); r3 = dpp_red8(r3); r4 = dpp_red8(r4);

        float sg = (r4 > 0.f) ? 1.f : ((r4 < 0.f) ? 0.f : 0.5f);
        // exp(|s|/8) = exp2(|s| * 0.125*log2(e))
        float mag2 = sqrtf(r2 * r2 + r3 * r3) * 0.180336880f;
        float ex = valid ? __builtin_exp2f(mag2) : 0.f;
        float wgt = fminf(ex * sg, 30000.f);   // f16-overflow guard
        l_run += ex;
        _Float16 wh = (_Float16)wgt;
        f16x2 wv = {wh, wh};
#pragma unroll
        for (int j = 0; j < 8; ++j) {
            f16x2 hs2 = __builtin_bit_cast(f16x2, pw[j]);
            ps[j] = ps[j] + wv * hs2;      // v_pk_fma_f16
        }
    };

    if (beg + e < end) ldE(beg + e, aR0, aR1, aP0, aP1);
    if (beg + 2 + e < end) ldE(beg + 2 + e, bR0, bR1, bP0, bP1);

    for (int pos = beg; pos < end; pos += 4) {
        process(aR0, aR1, aP0, aP1, (pos + e) < end);
        if (pos + 4 + e < end) ldE(pos + 4 + e, aR0, aR1, aP0, aP1);
        else { aR0 = make_float4(0, 0, 0, 0); aR1 = aR0; aP0 = make_uint4(0, 0, 0, 0); aP1 = aP0; }
        if (pos + 2 >= end) break;
        process(bR0, bR1, bP0, bP1, (pos + 2 + e) < end);
        if (pos + 6 + e < end) ldE(pos + 6 + e, bR0, bR1, bP0, bP1);
        else { bR0 = make_float4(0, 0, 0, 0); bR1 = bR0; bP0 = make_uint4(0, 0, 0, 0); bP1 = bP0; }
    }

    // merge the two halves (packed adds)
#pragma unroll
    for (int j = 0; j < 8; ++j) {
        unsigned o = __shfl_xor(__builtin_bit_cast(unsigned, ps[j]), 32, 64);
        ps[j] = ps[j] + __builtin_bit_cast(f16x2, o);
    }
    l_run += __shfl_xor(l_run, 32, 64);

    // deg-0 nodes: l_run == 0 -> S must be 0 (NOT inf; (f16)1e16 = inf, 0*inf = NaN)
    float inv = (l_run > 0.f) ? (1.0f / l_run) : 0.f;
    if (e == 0) {
        _Float16 ih = (_Float16)inv;
        f16x2 iv = {ih, ih};
        uint4 o0, o1;
        unsigned* op0 = &o0.x;
        unsigned* op1 = &o1.x;
#pragma unroll
        for (int j = 0; j < 4; ++j) {
            op0[j] = __builtin_bit_cast(unsigned, (f16x2)(ps[j] * iv));
            op1[j] = __builtin_bit_cast(unsigned, (f16x2)(ps[j + 4] * iv));
        }
        _Float16* sp = Sb + (size_t)n * 512 + g * 128 + d0 * 2;
        *(uint4*)sp = o0;
        *(uint4*)(sp + 8) = o1;
    }
}

// ---------------- K5_ws v2: 32 nodes/block, column-split wave pairs -------------------
__global__ __launch_bounds__(256) void k5_ws(
    const float* __restrict__ h_re, const float* __restrict__ h_im,
    const _Float16* __restrict__ Sb,
    const _Float16* __restrict__ B2c,
    const float* __restrict__ gate_raw, const float* __restrict__ modrelu_b,
    float2* __restrict__ out) {
    __shared__ float xch[2][32][8];
    int w = threadIdx.x >> 6, l = threadIdx.x & 63;
    int r = l & 15, g = l >> 4;
    int nh = w >> 1, ct = w & 1;
    int nbase = blockIdx.x * 32;
    int n0 = nbase + nh * 16;
    int nodeA = min(n0 + r, NN - 1);
    int q0 = 2 * ct;
    const int nt_[4] = {q0, q0 + 1, 4 + q0, 5 + q0};
    int slot8 = ((r << 2) + g) << 3;

    const _Float16* abase = Sb + (size_t)nodeA * 512 + g * 8;
    const _Float16* bbase = B2c + slot8;

    f32x4 acc[4];
#pragma unroll
    for (int t = 0; t < 4; ++t) acc[t] = {0.f, 0.f, 0.f, 0.f};

    f16x8 Ac = *(const f16x8*)(abase);
    f16x8 Bc0 = *(const f16x8*)(bbase + nt_[0] * 512);
    f16x8 Bc1 = *(const f16x8*)(bbase + nt_[1] * 512);
    f16x8 Bc2 = *(const f16x8*)(bbase + nt_[2] * 512);
    f16x8 Bc3 = *(const f16x8*)(bbase + nt_[3] * 512);
#pragma unroll
    for (int ch = 0; ch < 16; ++ch) {
        f16x8 An = Ac, Bn0 = Bc0, Bn1 = Bc1, Bn2 = Bc2, Bn3 = Bc3;
        if (ch + 1 < 16) {
            An = *(const f16x8*)(abase + (ch + 1) * 32);
            const _Float16* bn = bbase + (ch + 1) * 4096;
            Bn0 = *(const f16x8*)(bn + nt_[0] * 512);
            Bn1 = *(const f16x8*)(bn + nt_[1] * 512);
            Bn2 = *(const f16x8*)(bn + nt_[2] * 512);
            Bn3 = *(const f16x8*)(bn + nt_[3] * 512);
        }
        acc[0] = __builtin_amdgcn_mfma_f32_16x16x32_f16(Ac, Bc0, acc[0], 0, 0, 0);
        acc[1] = __builtin_amdgcn_mfma_f32_16x16x32_f16(Ac, Bc1, acc[1], 0, 0, 0);
        acc[2] = __builtin_amdgcn_mfma_f32_16x16x32_f16(Ac, Bc2, acc[2], 0, 0, 0);
        acc[3] = __builtin_amdgcn_mfma_f32_16x16x32_f16(Ac, Bc3, acc[3], 0, 0, 0);
        Ac = An; Bc0 = Bn0; Bc1 = Bn1; Bc2 = Bn2; Bc3 = Bn3;
    }

    float gate = 1.0f / (1.0f + expf(-gate_raw[0]));
    float bo[2];
#pragma unroll
    for (int qq = 0; qq < 2; ++qq) bo[qq] = modrelu_b[(q0 + qq) * 16 + r];

    float hr[4][2], hi[4][2];
#pragma unroll
    for (int j = 0; j < 4; ++j) {
        int nc = min(n0 + g * 4 + j, NN - 1);
#pragma unroll
        for (int qq = 0; qq < 2; ++qq) {
            int o = (q0 + qq) * 16 + r;
            hr[j][qq] = h_re[nc * DIM + o];
            hi[j][qq] = h_im[nc * DIM + o];
        }
    }

    float tsr_p[4], tsi_p[4], hn2_p[4];
#pragma unroll
    for (int j = 0; j < 4; ++j) {
        float tsr = 0.f, tsi = 0.f, hn2 = 0.f;
#pragma unroll
        for (int qq = 0; qq < 2; ++qq) {
            float ur = acc[qq][j], ui = acc[2 + qq][j];
            tsr += hr[j][qq] * ur + hi[j][qq] * ui;
            tsi += hr[j][qq] * ui - hi[j][qq] * ur;
            hn2 += hr[j][qq] * hr[j][qq] + hi[j][qq] * hi[j][qq];
        }
#pragma unroll
        for (int off = 1; off < 16; off <<= 1) {
            tsr += __shfl_xor(tsr, off, 64);
            tsi += __shfl_xor(tsi, off, 64);
            hn2 += __shfl_xor(hn2, off, 64);
        }
        tsr_p[j] = tsr; tsi_p[j] = tsi; hn2_p[j] = hn2;
        if (r == 0) {
            int nloc = nh * 16 + g * 4 + j;
            xch[ct][nloc][0] = tsr;
            xch[ct][nloc][1] = tsi;
            xch[ct][nloc][2] = hn2;
        }
    }
    __syncthreads();

    float Tsr[4], Tsi[4];
#pragma unroll
    for (int j = 0; j < 4; ++j) {
        int nloc = nh * 16 + g * 4 + j;
        float tsr = tsr_p[j] + xch[1 - ct][nloc][0];
        float tsi = tsi_p[j] + xch[1 - ct][nloc][1];
        float hn2 = hn2_p[j] + xch[1 - ct][nloc][2];
        float cfac = gate * SIC / fmaxf(hn2, 1e-6f);
        Tsr[j] = cfac * tsr; Tsi[j] = cfac * tsi;
    }

    float xr_[4][2], xi_[4][2];
    float sr_p[4], si_p[4], qr_p[4], qi_p[4];
#pragma unroll
    for (int j = 0; j < 4; ++j) {
        float sr = 0.f, si = 0.f, qr = 0.f, qi = 0.f;
#pragma unroll
        for (int qq = 0; qq < 2; ++qq) {
            float hrv = hr[j][qq], hiv = hi[j][qq];
            float nre = hrv + acc[qq][j]     - (Tsr[j] * hrv - Tsi[j] * hiv);
            float nim = hiv + acc[2 + qq][j] - (Tsr[j] * hiv + Tsi[j] * hrv);
            xr_[j][qq] = nre; xi_[j][qq] = nim;
            sr += nre; si += nim; qr += nre * nre; qi += nim * nim;
        }
#pragma unroll
        for (int off = 1; off < 16; off <<= 1) {
            sr += __shfl_xor(sr, off, 64);
            si += __shfl_xor(si, off, 64);
            qr += __shfl_xor(qr, off, 64);
            qi += __shfl_xor(qi, off, 64);
        }
        sr_p[j] = sr; si_p[j] = si; qr_p[j] = qr; qi_p[j] = qi;
        if (r == 0) {
            int nloc = nh * 16 + g * 4 + j;
            xch[ct][nloc][4] = sr;
            xch[ct][nloc][5] = si;
            xch[ct][nloc][6] = qr;
            xch[ct][nloc][7] = qi;
        }
    }
    __syncthreads();

#pragma unroll
    for (int j = 0; j < 4; ++j) {
        int nloc = nh * 16 + g * 4 + j;
        int n = n0 + g * 4 + j;
        float sr = sr_p[j] + xch[1 - ct][nloc][4];
        float si = si_p[j] + xch[1 - ct][nloc][5];
        float qr = qr_p[j] + xch[1 - ct][nloc][6];
        float qi = qi_p[j] + xch[1 - ct][nloc][7];
        float mean_r = sr * (1.f / DIM), mean_i = si * (1.f / DIM);
        float var_r = (qr - DIM * mean_r * mean_r) * (1.f / (DIM - 1));
        float var_i = (qi - DIM * mean_i * mean_i) * (1.f / (DIM - 1));
        float std_r = fmaxf(sqrtf(fmaxf(var_r, 0.f)), 1e-5f);
        float std_i = fmaxf(sqrtf(fmaxf(var_i, 0.f)), 1e-5f);
        if (n < NN) {
#pragma unroll
            for (int qq = 0; qq < 2; ++qq) {
                float xr = (xr_[j][qq] - mean_r) / std_r;
                float xi = (xi_[j][qq] - mean_i) / std_i;
                float mag = fmaxf(sqrtf(xr * xr + xi * xi), 1e-6f);
                float gg = fmaxf(mag + bo[qq], 0.f);
                float sc = gg / mag;
                out[n * DIM + (q0 + qq) * 16 + r] = make_float2(xr * sc, xi * sc);
            }
        }
    }
}

extern "C" void kernel_launch(void* const* d_in, const int* in_sizes, int n_in,
                              void* d_out, int out_size, void* d_ws, size_t ws_size,
                              hipStream_t stream) {
    const float* h_re = (const float*)d_in[0];
    const float* h_im = (const float*)d_in[1];
    const float* W_re = (const float*)d_in[2];
    const float* W_im = (const float*)d_in[3];
    const float* Q_re = (const float*)d_in[4];
    const float* Q_im = (const float*)d_in[5];
    const float* gate_raw = (const float*)d_in[6];
    const float* b = (const float*)d_in[7];
    const int* src = (const int*)d_in[8];
    const int* dst = (const int*)d_in[9];

    char* ws = (char*)d_ws;
    size_t off = 0;
    auto alloc = [&](size_t bytes) {
        void* p = ws + off;
        off = (off + bytes + 255) & ~(size_t)255;
        return p;
    };
    _Float16* Sb = (_Float16*)alloc((size_t)NN * 512 * sizeof(_Float16));     // 51.2MB
    _Float16* BtQ = (_Float16*)alloc((size_t)512 * 128 * sizeof(_Float16));
    _Float16* BtWH = (_Float16*)alloc((size_t)512 * 128 * sizeof(_Float16));
    _Float16* B2c = (_Float16*)alloc((size_t)128 * 512 * sizeof(_Float16));
    unsigned* P16 = (unsigned*)alloc((size_t)NN * 64 * sizeof(unsigned));     // 12.8MB
    unsigned* W16 = (unsigned*)alloc((size_t)NN * 256 * sizeof(unsigned));    // 51.2MB
    int* counts = (int*)alloc((size_t)NN * sizeof(int));
    int* row_ptr = (int*)alloc((size_t)(NN + 1) * sizeof(int));
    int* cursor = (int*)alloc((size_t)NN * sizeof(int));
    int* sorted_src = (int*)alloc((size_t)NE * sizeof(int));
    int* bsum = (int*)alloc((size_t)NBLK * sizeof(int));
    int* bpre = (int*)alloc((size_t)(NBLK + 1) * sizeof(int));

    hipMemsetAsync(counts, 0, (size_t)NN * sizeof(int), stream);
    k_pre<<<(SE + 255) / 256, 256, 0, stream>>>(h_re, h_im, W_re, W_im, Q_re, Q_im, dst,
                                                BtQ, BtWH, B2c, P16, counts);
    k1f<<<4 * ((NN + 127) / 128), 256, 0, stream>>>(P16, BtQ, BtWH, W16);
    k2b1<<<NBLK, 256, 0, stream>>>(counts, bsum);
    k2b2<<<1, 256, 0, stream>>>(bsum, bpre);
    k2b3<<<NBLK, 256, 0, stream>>>(counts, bpre, row_ptr, cursor);
    k2c_fill<<<(NE + 255) / 256, 256, 0, stream>>>(src, dst, cursor, sorted_src);
    k_main<<<NN / 2, 128, 0, stream>>>(h_re, P16, W16, row_ptr, sorted_src, Sb);
    k5_ws<<<(NN + 31) / 32, 256, 0, stream>>>(h_re, h_im, Sb, B2c, gate_raw, b, (float2*)d_out);
}